// Round 1
// baseline (31.079 us; speedup 1.0000x reference)
//
#include <hip/hip_runtime.h>
#include <math.h>

// Problem constants (from the reference file)
constexpr int B_   = 128;
constexpr int S_   = 2048;
constexpr int EMB_ = 128;
constexpr int HID_ = 256;
constexpr int OUT_ = 32;

// One block per batch element. 512 threads:
//   tid 0..255   -> forward direction, hidden unit h = tid
//   tid 256..511 -> backward direction, hidden unit h = tid-256
// Each thread computes gates i, g, o (f-gate is dead: c=0) as 3 dot
// products of length EMB against the staged embedding row in LDS.
__global__ __launch_bounds__(512, 2) void bilstm_fused(
    const int*   __restrict__ inputs,
    const float* __restrict__ weight,
    const float* __restrict__ Wxf, const float* __restrict__ bxf, const float* __restrict__ bhf,
    const float* __restrict__ Wxb, const float* __restrict__ bxb, const float* __restrict__ bhb,
    const float* __restrict__ Why, const float* __restrict__ by,
    float*       __restrict__ out)
{
    __shared__ __align__(16) float xs[2][EMB_];    // [0]=x at t=S-1 (fwd), [1]=x at t=0 (bwd)
    __shared__ __align__(16) float hy2[2][HID_];   // per-direction hidden outputs
    __shared__ __align__(16) float hsum[HID_];     // hy_f + hy_b
    __shared__ float logits_s[OUT_];

    const int b   = blockIdx.x;
    const int tid = threadIdx.x;

    // ---- stage the two embedding rows into LDS (256 threads, 1 float each)
    if (tid < 2 * EMB_) {
        const int dir = tid >> 7;            // 0: fwd (last token), 1: bwd (first token)
        const int e   = tid & (EMB_ - 1);
        const int tok = inputs[(size_t)b * S_ + (dir ? 0 : (S_ - 1))];
        xs[dir][e] = weight[(size_t)tok * EMB_ + e];
    }
    __syncthreads();

    // ---- per-thread: 3 gate dot products (i, g, o), float4-vectorized
    const int h   = tid & (HID_ - 1);
    const int dir = tid >> 8;
    const float* Wx = dir ? Wxb : Wxf;
    const float* bx = dir ? bxb : bxf;
    const float* bh = dir ? bhb : bhf;

    float gi = bx[h]            + bh[h];             // input gate row:  h
    float gg = bx[2 * HID_ + h] + bh[2 * HID_ + h];  // cell gate row:   512+h
    float go = bx[3 * HID_ + h] + bh[3 * HID_ + h];  // output gate row: 768+h

    const float4* xv = reinterpret_cast<const float4*>(xs[dir]);
    const float4* wi = reinterpret_cast<const float4*>(Wx + (size_t)h * EMB_);
    const float4* wg = reinterpret_cast<const float4*>(Wx + (size_t)(2 * HID_ + h) * EMB_);
    const float4* wo = reinterpret_cast<const float4*>(Wx + (size_t)(3 * HID_ + h) * EMB_);

    #pragma unroll 4
    for (int k = 0; k < EMB_ / 4; ++k) {
        const float4 x4 = xv[k];
        const float4 a  = wi[k];
        const float4 c  = wg[k];
        const float4 d  = wo[k];
        gi = fmaf(x4.x, a.x, fmaf(x4.y, a.y, fmaf(x4.z, a.z, fmaf(x4.w, a.w, gi))));
        gg = fmaf(x4.x, c.x, fmaf(x4.y, c.y, fmaf(x4.z, c.z, fmaf(x4.w, c.w, gg))));
        go = fmaf(x4.x, d.x, fmaf(x4.y, d.y, fmaf(x4.z, d.z, fmaf(x4.w, d.w, go))));
    }

    const float si = 1.0f / (1.0f + expf(-gi));
    const float so = 1.0f / (1.0f + expf(-go));
    const float cy = si * tanhf(gg);
    hy2[dir][h] = so * tanhf(cy);
    __syncthreads();

    if (tid < HID_) hsum[tid] = hy2[0][tid] + hy2[1][tid];
    __syncthreads();

    // ---- logits: 32 threads, each a 256-length dot (float4 from LDS + L2)
    if (tid < OUT_) {
        float acc = by[tid];
        const float4* wv = reinterpret_cast<const float4*>(Why + (size_t)tid * HID_);
        const float4* hv = reinterpret_cast<const float4*>(hsum);
        #pragma unroll 8
        for (int k = 0; k < HID_ / 4; ++k) {
            const float4 h4 = hv[k];
            const float4 w4 = wv[k];
            acc = fmaf(h4.x, w4.x, fmaf(h4.y, w4.y, fmaf(h4.z, w4.z, fmaf(h4.w, w4.w, acc))));
        }
        logits_s[tid] = acc;
    }
    __syncthreads();

    // ---- log-softmax over 32 logits: wave 0, lanes 0..31, shuffle reduce.
    // xor masks <=16 keep sources within active lanes 0..31.
    if (tid < OUT_) {
        const float v = logits_s[tid];
        float m = v;
        #pragma unroll
        for (int off = 16; off; off >>= 1) m = fmaxf(m, __shfl_xor(m, off));
        float s = expf(v - m);
        #pragma unroll
        for (int off = 16; off; off >>= 1) s += __shfl_xor(s, off);
        out[(size_t)b * OUT_ + tid] = v - m - logf(s);
    }
}

extern "C" void kernel_launch(void* const* d_in, const int* in_sizes, int n_in,
                              void* d_out, int out_size, void* d_ws, size_t ws_size,
                              hipStream_t stream) {
    // setup_inputs() order:
    // 0 inputs [B,S] int32      1 weight [VOCAB,EMB] f32
    // 2 Wxf [1024,128]  3 bxf [1024]  4 Whf [1024,256] (dead)  5 bhf [1024]
    // 6 Wxb [1024,128]  7 bxb [1024]  8 Whb [1024,256] (dead)  9 bhb [1024]
    // 10 Why [32,256]   11 by [32]
    const int*   inputs = (const int*)  d_in[0];
    const float* weight = (const float*)d_in[1];
    const float* Wxf    = (const float*)d_in[2];
    const float* bxf    = (const float*)d_in[3];
    const float* bhf    = (const float*)d_in[5];
    const float* Wxb    = (const float*)d_in[6];
    const float* bxb    = (const float*)d_in[7];
    const float* bhb    = (const float*)d_in[9];
    const float* Why    = (const float*)d_in[10];
    const float* by     = (const float*)d_in[11];
    float* out = (float*)d_out;

    bilstm_fused<<<B_, 512, 0, stream>>>(inputs, weight,
                                         Wxf, bxf, bhf,
                                         Wxb, bxb, bhb,
                                         Why, by, out);
}

// Round 2
// 22.925 us; speedup vs baseline: 1.3557x; 1.3557x over previous
//
#include <hip/hip_runtime.h>
#include <math.h>

// Problem constants (from the reference file)
constexpr int B_   = 128;
constexpr int S_   = 2048;
constexpr int EMB_ = 128;
constexpr int HID_ = 256;
constexpr int OUT_ = 32;

// ws layout:
//   [0, 2MB)      : WT4[dir][k][h] float4 = {Wx_i, Wx_g, Wx_o, 0} transposed pack
//   [2MB, 2MB+32KB): partial logits [b][dir][32]
// (ws is >= 256 MB per the harness poison fill; we use ~2.1 MB)
constexpr size_t WT4_ELEMS   = (size_t)2 * EMB_ * HID_;  // float4 count = 65536 (1 MB... x4 floats = 2 MB? no: 65536 float4 = 1 MB*... 65536*16B = 1 MB) 
// NOTE: 2 dirs * 128 k * 256 h = 65536 float4 = 1 MB total.
constexpr size_t LOGITS_OFF  = 2ull << 20;               // 2 MB offset (comfortably past WT4)

// ---------------------------------------------------------------------------
// Kernel A: transpose+pack weights.
// Thread t -> (dir, h, k) with k fastest => reads of Wx rows are coalesced
// (64 consecutive k per wave). Writes are uncoalesced float4 (one per thread,
// one-time 1 MB — cheap).
__global__ __launch_bounds__(256) void pack_weights(
    const float* __restrict__ Wxf, const float* __restrict__ Wxb,
    float4* __restrict__ wt4)
{
    const int t   = blockIdx.x * 256 + threadIdx.x;       // 0 .. 65535
    const int k   = t & (EMB_ - 1);
    const int h   = (t >> 7) & (HID_ - 1);
    const int dir = t >> 15;
    const float* src = dir ? Wxb : Wxf;
    const float wi = src[(size_t)(0 * HID_ + h) * EMB_ + k];   // input gate
    const float wg = src[(size_t)(2 * HID_ + h) * EMB_ + k];   // cell gate
    const float wo = src[(size_t)(3 * HID_ + h) * EMB_ + k];   // output gate
    wt4[((size_t)(dir * EMB_ + k) * HID_) + h] = make_float4(wi, wg, wo, 0.0f);
}

// ---------------------------------------------------------------------------
// Kernel B: one block per (b, dir). 256 threads, thread = hidden unit h.
// Inner loop over k: x[k] broadcast from LDS, coalesced float4 weight read
// (lanes h-consecutive => 1 KB/wave/instr). Emits partial logits (linear in
// hy, so per-direction contributions just add).
__global__ __launch_bounds__(256) void gates_partial(
    const int*   __restrict__ inputs,
    const float* __restrict__ weight,
    const float4* __restrict__ wt4,
    const float* __restrict__ bxf, const float* __restrict__ bhf,
    const float* __restrict__ bxb, const float* __restrict__ bhb,
    const float* __restrict__ Why,
    float*       __restrict__ wsL)
{
    __shared__ __align__(16) float xs[EMB_];
    __shared__ __align__(16) float hy[HID_];

    const int blk = blockIdx.x;
    const int b   = blk >> 1;
    const int dir = blk & 1;
    const int tid = threadIdx.x;

    if (tid < EMB_) {
        const int tok = inputs[(size_t)b * S_ + (dir ? 0 : (S_ - 1))];
        xs[tid] = weight[(size_t)tok * EMB_ + tid];
    }
    __syncthreads();

    const float* bx = dir ? bxb : bxf;
    const float* bh = dir ? bhb : bhf;
    const int h = tid;

    float gi = bx[h]            + bh[h];
    float gg = bx[2 * HID_ + h] + bh[2 * HID_ + h];
    float go = bx[3 * HID_ + h] + bh[3 * HID_ + h];

    const float4* wp = wt4 + (size_t)dir * EMB_ * HID_ + h;
    #pragma unroll 8
    for (int k = 0; k < EMB_; ++k) {
        const float4 w = wp[(size_t)k * HID_];
        const float  x = xs[k];
        gi = fmaf(x, w.x, gi);
        gg = fmaf(x, w.y, gg);
        go = fmaf(x, w.z, go);
    }

    const float si = 1.0f / (1.0f + expf(-gi));
    const float so = 1.0f / (1.0f + expf(-go));
    hy[h] = so * tanhf(si * tanhf(gg));
    __syncthreads();

    // partial logits for this direction (32 threads; Why row per thread)
    if (tid < OUT_) {
        float acc = 0.0f;
        const float4* wv = reinterpret_cast<const float4*>(Why + (size_t)tid * HID_);
        const float4* hv = reinterpret_cast<const float4*>(hy);
        #pragma unroll 8
        for (int k = 0; k < HID_ / 4; ++k) {
            const float4 h4 = hv[k];
            const float4 w4 = wv[k];
            acc = fmaf(h4.x, w4.x, fmaf(h4.y, w4.y, fmaf(h4.z, w4.z, fmaf(h4.w, w4.w, acc))));
        }
        wsL[((size_t)b * 2 + dir) * OUT_ + tid] = acc;
    }
}

// ---------------------------------------------------------------------------
// Kernel C: combine directions, add by, log-softmax over 32. One block per b.
__global__ __launch_bounds__(64) void epilogue(
    const float* __restrict__ wsL,
    const float* __restrict__ by,
    float*       __restrict__ out)
{
    const int b = blockIdx.x;
    const int t = threadIdx.x;
    if (t < OUT_) {
        const float v = wsL[((size_t)b * 2 + 0) * OUT_ + t]
                      + wsL[((size_t)b * 2 + 1) * OUT_ + t]
                      + by[t];
        float m = v;
        #pragma unroll
        for (int off = 16; off; off >>= 1) m = fmaxf(m, __shfl_xor(m, off, 32));
        float s = expf(v - m);
        #pragma unroll
        for (int off = 16; off; off >>= 1) s += __shfl_xor(s, off, 32);
        out[(size_t)b * OUT_ + t] = v - m - logf(s);
    }
}

extern "C" void kernel_launch(void* const* d_in, const int* in_sizes, int n_in,
                              void* d_out, int out_size, void* d_ws, size_t ws_size,
                              hipStream_t stream) {
    // setup_inputs() order:
    // 0 inputs [B,S] int32      1 weight [VOCAB,EMB] f32
    // 2 Wxf [1024,128]  3 bxf [1024]  4 Whf (dead)  5 bhf [1024]
    // 6 Wxb [1024,128]  7 bxb [1024]  8 Whb (dead)  9 bhb [1024]
    // 10 Why [32,256]   11 by [32]
    const int*   inputs = (const int*)  d_in[0];
    const float* weight = (const float*)d_in[1];
    const float* Wxf    = (const float*)d_in[2];
    const float* bxf    = (const float*)d_in[3];
    const float* bhf    = (const float*)d_in[5];
    const float* Wxb    = (const float*)d_in[6];
    const float* bxb    = (const float*)d_in[7];
    const float* bhb    = (const float*)d_in[9];
    const float* Why    = (const float*)d_in[10];
    const float* by     = (const float*)d_in[11];
    float* out = (float*)d_out;

    float4* wt4 = (float4*)d_ws;
    float*  wsL = (float*)((char*)d_ws + LOGITS_OFF);

    pack_weights<<<256, 256, 0, stream>>>(Wxf, Wxb, wt4);
    gates_partial<<<B_ * 2, 256, 0, stream>>>(inputs, weight, wt4,
                                              bxf, bhf, bxb, bhb, Why, wsL);
    epilogue<<<B_, 64, 0, stream>>>(wsL, by, out);
}

// Round 3
// 13.772 us; speedup vs baseline: 2.2567x; 1.6647x over previous
//
#include <hip/hip_runtime.h>
#include <math.h>

// Problem constants (from the reference file)
constexpr int B_   = 128;
constexpr int S_   = 2048;
constexpr int EMB_ = 128;
constexpr int HID_ = 256;
constexpr int OUT_ = 32;

constexpr int HT   = 8;         // h per block (per direction)
constexpr int BH   = 64;        // b per block (half the batch)
constexpr int PADK = EMB_ + 4;  // 132 floats = 528 B: 16B-aligned rows, stride%32==4 -> conflict-free b128

// ws layout: hy[2][B][HID] floats at offset 0 (256 KB). Fully rewritten every call.

// ---------------------------------------------------------------------------
// Kernel 1: tiled GEMM for the gates + activations.
// grid = 2 dirs x 32 h-tiles x 2 b-halves = 128 blocks, 512 threads.
// Per block: stage X tile (64 emb rows) + 24 weight rows (i,g,o x 8 h) in LDS,
// then thread (hl, bg) computes 3 dots of length 128 entirely from LDS.
// Weights are read from global exactly once across the whole grid.
__global__ __launch_bounds__(512) void gates_gemm(
    const int*   __restrict__ inputs,
    const float* __restrict__ weight,
    const float* __restrict__ Wxf, const float* __restrict__ bxf, const float* __restrict__ bhf,
    const float* __restrict__ Wxb, const float* __restrict__ bxb, const float* __restrict__ bhb,
    float*       __restrict__ hy_ws)            // [2][B][HID]
{
    __shared__ __align__(16) float Xs[BH][PADK];      // 33.8 KB
    __shared__ __align__(16) float Ws[3][HT][PADK];   // 12.7 KB
    __shared__ int toks[BH];

    const int blk   = blockIdx.x;
    const int dir   = blk >> 6;          // 64 blocks per direction
    const int ht    = (blk & 63) >> 1;   // 0..31
    const int bhalf = blk & 1;
    const int h0    = ht * HT;
    const int tid   = threadIdx.x;

    if (tid < BH)
        toks[tid] = inputs[(size_t)(bhalf * BH + tid) * S_ + (dir ? 0 : (S_ - 1))];
    __syncthreads();

    // ---- stage X: 64 rows x 32 float4 = 2048 float4, 4 passes of 512
    #pragma unroll
    for (int p = 0; p < 4; ++p) {
        const int idx = p * 512 + tid;
        const int bl  = idx >> 5;        // 0..63
        const int j   = idx & 31;
        const float4 v = reinterpret_cast<const float4*>(weight + (size_t)toks[bl] * EMB_)[j];
        *reinterpret_cast<float4*>(&Xs[bl][4 * j]) = v;
    }
    // ---- stage W: 3 gates x 8 rows x 32 float4 = 768 float4
    {
        const float* Wx = dir ? Wxb : Wxf;
        for (int idx = tid; idx < 3 * HT * 32; idx += 512) {
            const int g   = idx >> 8;            // 0..2  (HT*32 = 256)
            const int rem = idx & 255;
            const int hl  = rem >> 5;
            const int j   = rem & 31;
            const int grow = (g == 0) ? 0 : ((g == 1) ? 2 : 3);  // i, g, o gate chunks
            const float4 v = reinterpret_cast<const float4*>(
                Wx + (size_t)(grow * HID_ + h0 + hl) * EMB_)[j];
            *reinterpret_cast<float4*>(&Ws[g][hl][4 * j]) = v;
        }
    }
    __syncthreads();

    // ---- compute: thread = (hl = tid&7, bg = tid>>3) -> one (b, h) pair
    const int hl = tid & (HT - 1);
    const int bg = tid >> 3;                 // 0..63
    const int b  = bhalf * BH + bg;
    const int h  = h0 + hl;

    const float* bx = dir ? bxb : bxf;
    const float* bh = dir ? bhb : bhf;
    float gi = bx[h]            + bh[h];
    float gg = bx[2 * HID_ + h] + bh[2 * HID_ + h];
    float go = bx[3 * HID_ + h] + bh[3 * HID_ + h];

    #pragma unroll 8
    for (int k4 = 0; k4 < EMB_ / 4; ++k4) {
        const float4 x  = *reinterpret_cast<const float4*>(&Xs[bg][4 * k4]);
        const float4 wi = *reinterpret_cast<const float4*>(&Ws[0][hl][4 * k4]);
        const float4 wg = *reinterpret_cast<const float4*>(&Ws[1][hl][4 * k4]);
        const float4 wo = *reinterpret_cast<const float4*>(&Ws[2][hl][4 * k4]);
        gi = fmaf(x.x, wi.x, fmaf(x.y, wi.y, fmaf(x.z, wi.z, fmaf(x.w, wi.w, gi))));
        gg = fmaf(x.x, wg.x, fmaf(x.y, wg.y, fmaf(x.z, wg.z, fmaf(x.w, wg.w, gg))));
        go = fmaf(x.x, wo.x, fmaf(x.y, wo.y, fmaf(x.z, wo.z, fmaf(x.w, wo.w, go))));
    }

    const float si = 1.0f / (1.0f + expf(-gi));
    const float so = 1.0f / (1.0f + expf(-go));
    hy_ws[((size_t)dir * B_ + b) * HID_ + h] = so * tanhf(si * tanhf(gg));
}

// ---------------------------------------------------------------------------
// Kernel 2: combine directions, logits (wave-per-output-row dot), log-softmax.
// 128 blocks (one per b), 512 threads = 8 waves.
__global__ __launch_bounds__(512) void epilogue(
    const float* __restrict__ hy_ws,
    const float* __restrict__ Why,
    const float* __restrict__ by,
    float*       __restrict__ out)
{
    __shared__ __align__(16) float hs[HID_];
    __shared__ float lg[OUT_];

    const int b   = blockIdx.x;
    const int tid = threadIdx.x;

    if (tid < HID_ / 4) {   // 64 threads, one float4 each
        const float4 f = reinterpret_cast<const float4*>(hy_ws + (size_t)b * HID_)[tid];
        const float4 r = reinterpret_cast<const float4*>(hy_ws + ((size_t)B_ + b) * HID_)[tid];
        *reinterpret_cast<float4*>(&hs[4 * tid]) =
            make_float4(f.x + r.x, f.y + r.y, f.z + r.z, f.w + r.w);
    }
    __syncthreads();

    const int w    = tid >> 6;     // wave 0..7
    const int lane = tid & 63;
    #pragma unroll
    for (int i = 0; i < OUT_ / 8; ++i) {       // 4 rows per wave
        const int o = w + 8 * i;
        const float4 wv = reinterpret_cast<const float4*>(Why + (size_t)o * HID_)[lane];
        const float4 hv = *reinterpret_cast<const float4*>(&hs[4 * lane]);
        float p = fmaf(hv.x, wv.x, fmaf(hv.y, wv.y, fmaf(hv.z, wv.z, hv.w * wv.w)));
        #pragma unroll
        for (int off = 32; off; off >>= 1) p += __shfl_xor(p, off);
        if (lane == 0) lg[o] = p + by[o];
    }
    __syncthreads();

    if (tid < OUT_) {
        const float v = lg[tid];
        float m = v;
        #pragma unroll
        for (int off = 16; off; off >>= 1) m = fmaxf(m, __shfl_xor(m, off));
        float s = expf(v - m);
        #pragma unroll
        for (int off = 16; off; off >>= 1) s += __shfl_xor(s, off);
        out[(size_t)b * OUT_ + tid] = v - m - logf(s);
    }
}

extern "C" void kernel_launch(void* const* d_in, const int* in_sizes, int n_in,
                              void* d_out, int out_size, void* d_ws, size_t ws_size,
                              hipStream_t stream) {
    // setup_inputs() order:
    // 0 inputs [B,S] int32      1 weight [VOCAB,EMB] f32
    // 2 Wxf [1024,128]  3 bxf [1024]  4 Whf (dead)  5 bhf [1024]
    // 6 Wxb [1024,128]  7 bxb [1024]  8 Whb (dead)  9 bhb [1024]
    // 10 Why [32,256]   11 by [32]
    const int*   inputs = (const int*)  d_in[0];
    const float* weight = (const float*)d_in[1];
    const float* Wxf    = (const float*)d_in[2];
    const float* bxf    = (const float*)d_in[3];
    const float* bhf    = (const float*)d_in[5];
    const float* Wxb    = (const float*)d_in[6];
    const float* bxb    = (const float*)d_in[7];
    const float* bhb    = (const float*)d_in[9];
    const float* Why    = (const float*)d_in[10];
    const float* by     = (const float*)d_in[11];
    float* out = (float*)d_out;

    float* hy_ws = (float*)d_ws;   // [2][B][HID] = 256 KB

    gates_gemm<<<2 * (HID_ / HT) * 2, 512, 0, stream>>>(
        inputs, weight, Wxf, bxf, bhf, Wxb, bxb, bhb, hy_ws);
    epilogue<<<B_, 512, 0, stream>>>(hy_ws, Why, by, out);
}